// Round 1
// baseline (355.478 us; speedup 1.0000x reference)
//
#include <hip/hip_runtime.h>

// Haar 3D LL band: out[b,c,d,h,w] = 2^-1.5 * sum of the 2x2x2 block of x.
// x: (2,16,128,128,128) f32, out: (2,16,64,64,64) f32.
// Memory-bound streaming kernel: 256 MiB read + 32 MiB write.
// Each thread: 4x float4 loads (2 d-rows x 2 h-rows), produces 2 outputs (float2 store).

#define BC    32      // B*C = 2*16
#define DIN   128
#define HIN   128
#define WIN   128
#define DOUT  64
#define HOUT  64
#define WOUT  64

__global__ __launch_bounds__(256) void WaveletTransform3D_kernel(
    const float* __restrict__ x, float* __restrict__ out) {
    const float SCALE = 0.35355339059327373f; // 2^-1.5

    int tid = blockIdx.x * blockDim.x + threadIdx.x;
    // thread -> (bc, dout, hout, w4) where w4 indexes pairs of output w (4 input w)
    int w4   = tid & 31;         // WOUT/2 = 32 pairs per row
    int t    = tid >> 5;
    int hout = t & 63;
    t >>= 6;
    int dout = t & 63;
    int bc   = t >> 6;           // 0..31

    const int d0 = dout << 1;
    const int h0 = hout << 1;
    const int w0 = w4 << 2;      // input w base (multiple of 4 -> 16B aligned)

    // base offset in float4 units
    const float4* __restrict__ p = reinterpret_cast<const float4*>(x);
    size_t b4 = (((size_t)(bc * DIN + d0) * HIN + h0) * WIN + w0) >> 2;
    const size_t hstride4 = WIN / 4;           // 32
    const size_t dstride4 = (size_t)HIN * WIN / 4; // 4096

    float4 v00 = p[b4];
    float4 v01 = p[b4 + hstride4];
    float4 v10 = p[b4 + dstride4];
    float4 v11 = p[b4 + dstride4 + hstride4];

    float o0 = (v00.x + v00.y) + (v01.x + v01.y) + (v10.x + v10.y) + (v11.x + v11.y);
    float o1 = (v00.z + v00.w) + (v01.z + v01.w) + (v10.z + v10.w) + (v11.z + v11.w);

    size_t obase = ((size_t)(bc * DOUT + dout) * HOUT + hout) * WOUT + (w4 << 1);
    float2 o;
    o.x = o0 * SCALE;
    o.y = o1 * SCALE;
    *reinterpret_cast<float2*>(out + obase) = o;
}

extern "C" void kernel_launch(void* const* d_in, const int* in_sizes, int n_in,
                              void* d_out, int out_size, void* d_ws, size_t ws_size,
                              hipStream_t stream) {
    const float* x = (const float*)d_in[0];
    float* out = (float*)d_out;
    // total threads: BC * DOUT * HOUT * (WOUT/2) = 32*64*64*32 = 4,194,304
    const int total = BC * DOUT * HOUT * (WOUT / 2);
    const int block = 256;
    const int grid = total / block; // 16384
    WaveletTransform3D_kernel<<<grid, block, 0, stream>>>(x, out);
}